// Round 1
// baseline (302.271 us; speedup 1.0000x reference)
//
#include <hip/hip_runtime.h>

typedef __attribute__((ext_vector_type(8))) short bf16x8;
typedef __attribute__((ext_vector_type(4))) float f32x4;

static constexpr int HH = 224, WW = 224;
static constexpr int CIN = 64;
static constexpr int HW = HH * WW;   // 50176

__device__ __forceinline__ ushort f2bf(float f) {
    unsigned u = __builtin_bit_cast(unsigned, f);
    u += 0x7FFFu + ((u >> 16) & 1u);   // round-to-nearest-even
    return (ushort)(u >> 16);
}

// ws layout (ushort units):
//   w1r  [0, 36864)        9*64*64 bf16, [ch][n][c]
//   w2r  [36864, 40960)    64*64 bf16
//   zp   [40960, 41024)    128 B of zeros (halo zero-page)
//   xt   [41024, +8*HW*64) x as bf16, [b][p=y*W+x][c]  (51.4 MB)
__global__ void prep_kernel(const float* __restrict__ W1, const float* __restrict__ W2,
                            ushort* __restrict__ ws, int nfill) {
    const int idx = blockIdx.x * 256 + threadIdx.x;
    if (idx < 36864) {
        const int ch = idx >> 12;
        const int n = (idx >> 6) & 63;
        const int c = idx & 63;
        ws[idx] = f2bf(W1[n * 576 + c * 9 + ch]);
    } else if (idx < 40960) {
        ws[idx] = f2bf(W2[idx - 36864]);
    } else if (idx < nfill) {
        ws[idx] = 0;
    }
}

// Transpose + convert: x fp32 [b][c][y][x] -> xt bf16 [b][p][c].
// Reads: 256 B coalesced per instr (lanes span 64 consecutive p, one channel).
// Writes: 16 B per lane at stride 128 B; all 8 channel-slices of each 128 B
// line are written within one block's lifetime -> L2 assembles full lines.
__global__ __launch_bounds__(256)
void xprep_kernel(const float* __restrict__ xin, ushort* __restrict__ xt) {
    const int b = blockIdx.y;
    const float* xg = xin + (size_t)b * (CIN * HW);
    ushort* xo = xt + (size_t)b * ((size_t)HW * 64);
    const int base = blockIdx.x * 1024 + threadIdx.x;
    #pragma unroll
    for (int it = 0; it < 4; ++it) {
        const int idx = base + it * 256;                 // [0, 401408)
        const int p = ((idx >> 9) << 6) | (idx & 63);    // px within batch
        const int cg = (idx >> 6) & 7;                   // 8-channel group
        bf16x8 o;
        #pragma unroll
        for (int j = 0; j < 8; ++j)
            o[j] = (short)f2bf(xg[(cg * 8 + j) * HW + p]);
        *reinterpret_cast<bf16x8*>(xo + (size_t)p * 64 + cg * 8) = o;
    }
}

#define GLD_LDS16(g, l) __builtin_amdgcn_global_load_lds(                  \
    (const __attribute__((address_space(1))) void*)(g),                    \
    (__attribute__((address_space(3))) void*)(l), 16, 0, 0)

// Fast path: x already bf16 pixel-major. Staging = 13 global_load_lds per
// wave (async DMA, no VALU convert, no ds_write). LDS layout identical to
// baseline: xs[p*64 + (c ^ ((p&7)*8))], achieved by pre-swizzling the
// per-lane GLOBAL source address (LDS dest stays linear, m173 pattern).
__global__ __launch_bounds__(256, 3)
void mlpconv_fast(const ushort* __restrict__ xt, const ushort* __restrict__ w1r,
                  const float* __restrict__ b1, const ushort* __restrict__ w2r,
                  const float* __restrict__ b2, const ushort* __restrict__ zp,
                  float* __restrict__ out) {
    __shared__ ushort xs[10 * 40 * 64];   // 51,200 B -> 3 blocks/CU

    const int tid = threadIdx.x;
    const int wave = tid >> 6;
    const int lane = tid & 63;
    const int l15 = lane & 15;
    const int quad = lane >> 4;

    const int x0 = blockIdx.x * 32;   // 7
    const int y0 = blockIdx.y * 8;    // 28
    const int b = blockIdx.z;         // 8

    const ushort* xtb = xt + (size_t)b * ((size_t)HW * 64);

    // Per-lane source swizzle: wave-issue covers 8 px x 8 ch-groups (1024 B).
    // Lane l fills LDS slot (px = l>>3, slot = l&7); slot s of px p holds
    // channel-group s ^ (p&7); p == i*8 + (l>>3) with (i*8 + r*40) % 8 == 0.
    const int lpx = lane >> 3;
    const int laneoff = lpx * 64 + (((lane & 7) ^ lpx) * 8);   // ushort offset

    for (int q = wave; q < 50; q += 4) {     // 10 rows x 5 segments of 8 px
        const int r = q / 5;
        const int i = q - 5 * r;
        const int gy = y0 + r - 1;
        const int gx0 = x0 - 4 + i * 8;
        const ushort* real = xtb + (long)(gy * WW + gx0) * 64 + laneoff;
        const bool ok = ((unsigned)gy < (unsigned)HH) &
                        ((unsigned)(gx0 + lpx) < (unsigned)WW);
        const ushort* src = ok ? real : zp;   // halo lanes read the zero page
        GLD_LDS16(src, &xs[(r * 40 + i * 8) * 64]);
    }

    float b1v[4];
    #pragma unroll
    for (int nt = 0; nt < 4; ++nt) b1v[nt] = b1[nt * 16 + l15];

    f32x4 acc[4][4];   // C layout: col=lane&15 (=n), row=quad*4+reg (=m)
    #pragma unroll
    for (int mt = 0; mt < 4; ++mt)
        #pragma unroll
        for (int nt = 0; nt < 4; ++nt)
            acc[mt][nt] = (f32x4){b1v[nt], b1v[nt], b1v[nt], b1v[nt]};

    asm volatile("s_waitcnt vmcnt(0)" ::: "memory");
    __syncthreads();

    // ---- main loop: 18 k-steps (9 taps x 2 halves of 32 ch), barrier-free
    #pragma unroll 2
    for (int ks = 0; ks < 18; ++ks) {
        const int ch = ks >> 1;
        const int s = ks & 1;
        const int dy = ch / 3, dx = ch - 3 * (ch / 3);
        const int ko = s * 32 + quad * 8;
        bf16x8 bfr[4];
        #pragma unroll
        for (int nt = 0; nt < 4; ++nt)
            bfr[nt] = *reinterpret_cast<const bf16x8*>(
                w1r + ch * 4096 + (nt * 16 + l15) * 64 + ko);
        const int kswz = ko ^ (((l15 + dx + 3) & 7) * 8);
        #pragma unroll
        for (int mt = 0; mt < 4; ++mt) {
            const int row = 2 * wave + (mt >> 1) + dy;
            const int col = (mt & 1) * 16 + l15 + dx + 3;
            const bf16x8 afr = *reinterpret_cast<const bf16x8*>(
                &xs[(row * 40 + col) * 64 + kswz]);
            #pragma unroll
            for (int nt = 0; nt < 4; ++nt)
                acc[mt][nt] = __builtin_amdgcn_mfma_f32_16x16x32_bf16(
                    afr, bfr[nt], acc[mt][nt], 0, 0, 0);
        }
    }

    __syncthreads();   // other waves may still read xs; about to overwrite as h-scratch

    // ---- epilogue: ReLU -> bf16 h (per-wave LDS, no barrier) -> GEMM2 -> +b2 -> store
    float4 b2q[4];
    #pragma unroll
    for (int it = 0; it < 4; ++it)
        b2q[it] = *reinterpret_cast<const float4*>(b2 + it * 16 + quad * 4);

    bf16x8 wa2[2][4];   // W2 A-fragments, mt-invariant
    #pragma unroll
    for (int k2 = 0; k2 < 2; ++k2)
        #pragma unroll
        for (int it = 0; it < 4; ++it)
            wa2[k2][it] = *reinterpret_cast<const bf16x8*>(
                w2r + (it * 16 + l15) * 64 + k2 * 32 + quad * 8);

    ushort* myh = &xs[wave * (16 * 72)];
    float* outg = out + (size_t)b * (64 * HH * WW);

    #pragma unroll
    for (int mt = 0; mt < 4; ++mt) {
        #pragma unroll
        for (int ni = 0; ni < 4; ++ni)
            #pragma unroll
            for (int r = 0; r < 4; ++r) {
                float v = acc[mt][ni][r];
                v = v > 0.f ? v : 0.f;
                myh[(quad * 4 + r) * 72 + ni * 16 + l15] = f2bf(v);
            }
        f32x4 acc2[4];   // D2: col=lane&15 (=px), row=quad*4+reg (=cout)
        #pragma unroll
        for (int it = 0; it < 4; ++it)
            acc2[it] = (f32x4){b2q[it].x, b2q[it].y, b2q[it].z, b2q[it].w};
        #pragma unroll
        for (int k2 = 0; k2 < 2; ++k2) {
            const bf16x8 hb = *reinterpret_cast<const bf16x8*>(
                &myh[l15 * 72 + k2 * 32 + quad * 8]);
            #pragma unroll
            for (int it = 0; it < 4; ++it)
                acc2[it] = __builtin_amdgcn_mfma_f32_16x16x32_bf16(
                    wa2[k2][it], hb, acc2[it], 0, 0, 0);
        }
        const int gy = y0 + 2 * wave + (mt >> 1);
        const int gx = x0 + (mt & 1) * 16 + l15;
        #pragma unroll
        for (int it = 0; it < 4; ++it)
            #pragma unroll
            for (int r = 0; r < 4; ++r) {
                const int o = it * 16 + quad * 4 + r;
                outg[(o * HH + gy) * WW + gx] = acc2[it][r];
            }
    }
}

// Fallback (workspace too small for xt): the verified baseline kernel.
__global__ __launch_bounds__(256, 3)
void mlpconv_kernel(const float* __restrict__ xin, const ushort* __restrict__ w1r,
                    const float* __restrict__ b1, const ushort* __restrict__ w2r,
                    const float* __restrict__ b2, float* __restrict__ out) {
    __shared__ ushort xs[10 * 40 * 64];

    const int tid = threadIdx.x;
    const int wave = tid >> 6;
    const int lane = tid & 63;
    const int l15 = lane & 15;
    const int quad = lane >> 4;

    const int x0 = blockIdx.x * 32;
    const int y0 = blockIdx.y * 8;
    const int b = blockIdx.z;

    const float* xg = xin + (size_t)b * (CIN * HH * WW);

    for (int e = tid; e < 6400; e += 256) {
        const int i = e % 10;
        const int t = e / 10;
        const int c = t & 63;
        const int r = t >> 6;
        const int gy = y0 + r - 1;
        const int gx4 = x0 - 4 + i * 4;
        float4 v = make_float4(0.f, 0.f, 0.f, 0.f);
        if (((unsigned)gy < (unsigned)HH) && ((unsigned)gx4 <= 220u))
            v = *reinterpret_cast<const float4*>(xg + (c * HH + gy) * WW + gx4);
        const int p0 = r * 40 + i * 4;
        xs[(p0 + 0) * 64 + (c ^ (((p0 + 0) & 7) * 8))] = f2bf(v.x);
        xs[(p0 + 1) * 64 + (c ^ (((p0 + 1) & 7) * 8))] = f2bf(v.y);
        xs[(p0 + 2) * 64 + (c ^ (((p0 + 2) & 7) * 8))] = f2bf(v.z);
        xs[(p0 + 3) * 64 + (c ^ (((p0 + 3) & 7) * 8))] = f2bf(v.w);
    }

    float b1v[4];
    #pragma unroll
    for (int nt = 0; nt < 4; ++nt) b1v[nt] = b1[nt * 16 + l15];

    f32x4 acc[4][4];
    #pragma unroll
    for (int mt = 0; mt < 4; ++mt)
        #pragma unroll
        for (int nt = 0; nt < 4; ++nt)
            acc[mt][nt] = (f32x4){b1v[nt], b1v[nt], b1v[nt], b1v[nt]};

    __syncthreads();

    #pragma unroll 2
    for (int ks = 0; ks < 18; ++ks) {
        const int ch = ks >> 1;
        const int s = ks & 1;
        const int dy = ch / 3, dx = ch - 3 * (ch / 3);
        const int ko = s * 32 + quad * 8;
        bf16x8 bfr[4];
        #pragma unroll
        for (int nt = 0; nt < 4; ++nt)
            bfr[nt] = *reinterpret_cast<const bf16x8*>(
                w1r + ch * 4096 + (nt * 16 + l15) * 64 + ko);
        const int kswz = ko ^ (((l15 + dx + 3) & 7) * 8);
        #pragma unroll
        for (int mt = 0; mt < 4; ++mt) {
            const int row = 2 * wave + (mt >> 1) + dy;
            const int col = (mt & 1) * 16 + l15 + dx + 3;
            const bf16x8 afr = *reinterpret_cast<const bf16x8*>(
                &xs[(row * 40 + col) * 64 + kswz]);
            #pragma unroll
            for (int nt = 0; nt < 4; ++nt)
                acc[mt][nt] = __builtin_amdgcn_mfma_f32_16x16x32_bf16(
                    afr, bfr[nt], acc[mt][nt], 0, 0, 0);
        }
    }

    __syncthreads();

    float4 b2q[4];
    #pragma unroll
    for (int it = 0; it < 4; ++it)
        b2q[it] = *reinterpret_cast<const float4*>(b2 + it * 16 + quad * 4);

    bf16x8 wa2[2][4];
    #pragma unroll
    for (int k2 = 0; k2 < 2; ++k2)
        #pragma unroll
        for (int it = 0; it < 4; ++it)
            wa2[k2][it] = *reinterpret_cast<const bf16x8*>(
                w2r + (it * 16 + l15) * 64 + k2 * 32 + quad * 8);

    ushort* myh = &xs[wave * (16 * 72)];
    float* outg = out + (size_t)b * (64 * HH * WW);

    #pragma unroll
    for (int mt = 0; mt < 4; ++mt) {
        #pragma unroll
        for (int ni = 0; ni < 4; ++ni)
            #pragma unroll
            for (int r = 0; r < 4; ++r) {
                float v = acc[mt][ni][r];
                v = v > 0.f ? v : 0.f;
                myh[(quad * 4 + r) * 72 + ni * 16 + l15] = f2bf(v);
            }
        f32x4 acc2[4];
        #pragma unroll
        for (int it = 0; it < 4; ++it)
            acc2[it] = (f32x4){b2q[it].x, b2q[it].y, b2q[it].z, b2q[it].w};
        #pragma unroll
        for (int k2 = 0; k2 < 2; ++k2) {
            const bf16x8 hb = *reinterpret_cast<const bf16x8*>(
                &myh[l15 * 72 + k2 * 32 + quad * 8]);
            #pragma unroll
            for (int it = 0; it < 4; ++it)
                acc2[it] = __builtin_amdgcn_mfma_f32_16x16x32_bf16(
                    wa2[k2][it], hb, acc2[it], 0, 0, 0);
        }
        const int gy = y0 + 2 * wave + (mt >> 1);
        const int gx = x0 + (mt & 1) * 16 + l15;
        #pragma unroll
        for (int it = 0; it < 4; ++it)
            #pragma unroll
            for (int r = 0; r < 4; ++r) {
                const int o = it * 16 + quad * 4 + r;
                outg[(o * HH + gy) * WW + gx] = acc2[it][r];
            }
    }
}

extern "C" void kernel_launch(void* const* d_in, const int* in_sizes, int n_in,
                              void* d_out, int out_size, void* d_ws, size_t ws_size,
                              hipStream_t stream) {
    const float* x  = (const float*)d_in[0];
    const float* W1 = (const float*)d_in[1];
    const float* b1 = (const float*)d_in[2];
    const float* W2 = (const float*)d_in[3];
    const float* b2 = (const float*)d_in[4];
    float* out = (float*)d_out;

    ushort* ws  = (ushort*)d_ws;
    ushort* w1r = ws;                 // 36,864 ushorts
    ushort* w2r = ws + 36864;         // 4,096 ushorts
    ushort* zp  = ws + 40960;         // 64 ushorts (zero page)
    ushort* xt  = ws + 41024;         // 8*HW*64 ushorts = 51.4 MB

    const size_t need = (size_t)41024 * 2 + (size_t)8 * HW * 64 * 2;
    const bool fast = ws_size >= need;

    prep_kernel<<<161, 256, 0, stream>>>(W1, W2, ws, fast ? 41024 : 40960);
    dim3 grid(WW / 32, HH / 8, 8);    // (7, 28, 8)
    if (fast) {
        xprep_kernel<<<dim3(392, 8), 256, 0, stream>>>(x, xt);
        mlpconv_fast<<<grid, dim3(256), 0, stream>>>(xt, w1r, b1, w2r, b2, zp, out);
    } else {
        mlpconv_kernel<<<grid, dim3(256), 0, stream>>>(x, w1r, b1, w2r, b2, out);
    }
}